// Round 1
// baseline (301.323 us; speedup 1.0000x reference)
//
#include <hip/hip_runtime.h>
#include <float.h>
#include <math.h>

#define TOKS 16384
#define HDIM 4096
#define NEXP 64
#define TB   32              // tokens per block
#define HC   16              // h-chunk per staging step
#define NWAVE 8              // waves per block
#define HSLICE (HDIM / NWAVE)  // 512 h per wave

// Block: 512 threads = 8 waves. Each block: 32 tokens x 64 experts.
// Wave w handles h in [w*512, w*512+512). Lane = (token 0..31, expert-half 0..1),
// acc[32] fp32 per lane. Per-wave private LDS staging -> no barriers in main loop.
__global__ __launch_bounds__(512, 4)
void topk_router_kernel(const float* __restrict__ x,
                        const float* __restrict__ wgt,
                        const float* __restrict__ bias,
                        float* __restrict__ out)
{
  __shared__ __align__(16) float smem[16384];  // 64 KB: staging (48 KB) then reduction (64 KB)
  const int tid  = threadIdx.x;
  const int lane = tid & 63;
  const int wv   = tid >> 6;                 // wave id 0..7
  const int tokBase = blockIdx.x * TB;

  float* ws = smem + wv * (NEXP * HC);                       // [64 e][16 h], 1024 floats/wave
  float* xs = smem + NWAVE * (NEXP * HC) + wv * (TB * HC);   // [16 h][32 tok], 512 floats/wave

  const int tok  = lane & 31;
  const int egrp = lane >> 5;

  float acc[32];
#pragma unroll
  for (int j = 0; j < 32; ++j) acc[j] = 0.f;

  const int hbase = wv * HSLICE;
  const int xlTok = lane >> 1;        // staging: 2 lanes per token row
  const int xlH   = (lane & 1) * 8;
  const int wlE   = lane >> 2;        // staging: 4 lanes per expert row
  const int wlP   = (lane & 3) * 4;

  const float* xptr = x   + (size_t)(tokBase + xlTok) * HDIM + hbase + xlH;
  const float* wptr = wgt + (size_t)wlE * HDIM + hbase + wlP;

  for (int c = 0; c < HSLICE / HC; ++c) {
    // ---- stage x: 32 tok x 16 h (transposed into LDS) ----
    const float4 xa = *(const float4*)(xptr + c * HC);
    const float4 xb = *(const float4*)(xptr + c * HC + 4);
    // ---- stage w: 64 e x 16 h ----
    const float4 w0 = *(const float4*)(wptr + c * HC);
    const float4 w1 = *(const float4*)(wptr + c * HC + (size_t)16 * HDIM);
    const float4 w2 = *(const float4*)(wptr + c * HC + (size_t)32 * HDIM);
    const float4 w3 = *(const float4*)(wptr + c * HC + (size_t)48 * HDIM);

    xs[(xlH + 0) * TB + xlTok] = xa.x;
    xs[(xlH + 1) * TB + xlTok] = xa.y;
    xs[(xlH + 2) * TB + xlTok] = xa.z;
    xs[(xlH + 3) * TB + xlTok] = xa.w;
    xs[(xlH + 4) * TB + xlTok] = xb.x;
    xs[(xlH + 5) * TB + xlTok] = xb.y;
    xs[(xlH + 6) * TB + xlTok] = xb.z;
    xs[(xlH + 7) * TB + xlTok] = xb.w;
    *(float4*)&ws[(wlE +  0) * HC + wlP] = w0;
    *(float4*)&ws[(wlE + 16) * HC + wlP] = w1;
    *(float4*)&ws[(wlE + 32) * HC + wlP] = w2;
    *(float4*)&ws[(wlE + 48) * HC + wlP] = w3;

    // producer == consumer wave; DS pipe is in-order per wave. Just stop the
    // compiler from hoisting the reads above the writes.
    __builtin_amdgcn_sched_barrier(0);

    float xr[HC];
#pragma unroll
    for (int h = 0; h < HC; ++h) xr[h] = xs[h * TB + tok];   // stride-1 + half-wave broadcast

#pragma unroll
    for (int j = 0; j < 32; ++j) {
      const float* wr = ws + (egrp * 32 + j) * HC;           // wave-uniform per half -> LDS broadcast
      const float4 a = *(const float4*)(wr + 0);
      const float4 b = *(const float4*)(wr + 4);
      const float4 d = *(const float4*)(wr + 8);
      const float4 e = *(const float4*)(wr + 12);
      float s = acc[j];
      s = fmaf(xr[0],  a.x, s); s = fmaf(xr[1],  a.y, s);
      s = fmaf(xr[2],  a.z, s); s = fmaf(xr[3],  a.w, s);
      s = fmaf(xr[4],  b.x, s); s = fmaf(xr[5],  b.y, s);
      s = fmaf(xr[6],  b.z, s); s = fmaf(xr[7],  b.w, s);
      s = fmaf(xr[8],  d.x, s); s = fmaf(xr[9],  d.y, s);
      s = fmaf(xr[10], d.z, s); s = fmaf(xr[11], d.w, s);
      s = fmaf(xr[12], e.x, s); s = fmaf(xr[13], e.y, s);
      s = fmaf(xr[14], e.z, s); s = fmaf(xr[15], e.w, s);
      acc[j] = s;
    }
    __builtin_amdgcn_sched_barrier(0);
  }

  // ---- cross-wave reduction over the 8 H-slices ----
  __syncthreads();  // staging regions about to be clobbered by partials
  {
    float* p = smem + wv * 2048 + tok * 64 + egrp * 32;      // part[wave][tok][exp]
#pragma unroll
    for (int j = 0; j < 32; j += 4)
      *(float4*)&p[j] = make_float4(acc[j], acc[j+1], acc[j+2], acc[j+3]);
  }
  __syncthreads();
  {
    const int t  = tid >> 4;            // 0..31
    const int e0 = (tid & 15) * 4;      // 0..60
    float4 s = *(const float4*)&smem[t * 64 + e0];
#pragma unroll
    for (int p = 1; p < 8; ++p) {
      const float4 q = *(const float4*)&smem[p * 2048 + t * 64 + e0];
      s.x += q.x; s.y += q.y; s.z += q.z; s.w += q.w;
    }
    const float4 b4 = *(const float4*)&bias[e0];
    s.x += b4.x; s.y += b4.y; s.z += b4.z; s.w += b4.w;
    *(float4*)&smem[t * 64 + e0] = s;   // final logits [32][64], own slot only
  }
  __syncthreads();

  // ---- top-8 + softmax: wave wv handles 4 tokens ----
  for (int tt = 0; tt < 4; ++tt) {
    const int t = wv * 4 + tt;
    float v = smem[t * 64 + lane];      // lane = expert id
    float myval = 0.f, m0 = 0.f;
    int myidx = 0;
#pragma unroll
    for (int k = 0; k < 8; ++k) {
      float bv = v;
      int   bi = lane;
#pragma unroll
      for (int off = 1; off < 64; off <<= 1) {   // argmax, min-index tiebreak (jax stable order)
        const float ov = __shfl_xor(bv, off);
        const int   oi = __shfl_xor(bi, off);
        if (ov > bv || (ov == bv && oi < bi)) { bv = ov; bi = oi; }
      }
      if (k == 0) m0 = bv;
      if (lane == k) { myval = bv; myidx = bi; }
      if (lane == bi) v = -FLT_MAX;     // bi is wave-uniform here
    }
    const float el = (lane < 8) ? expf(myval - m0) : 0.f;
    float ssum = el;
    ssum += __shfl_xor(ssum, 1);
    ssum += __shfl_xor(ssum, 2);
    ssum += __shfl_xor(ssum, 4);
    if (lane < 8) {
      const size_t tg = (size_t)(tokBase + t);
      out[tg * 8 + lane] = el / ssum;                         // output 0: weights (f32)
      out[(size_t)TOKS * 8 + tg * 8 + lane] = (float)myidx;   // output 1: indices as f32
    }
  }
}

extern "C" void kernel_launch(void* const* d_in, const int* in_sizes, int n_in,
                              void* d_out, int out_size, void* d_ws, size_t ws_size,
                              hipStream_t stream) {
  const float* x    = (const float*)d_in[0];
  const float* wgt  = (const float*)d_in[1];
  const float* bias = (const float*)d_in[2];
  float* out = (float*)d_out;
  hipLaunchKernelGGL(topk_router_kernel, dim3(TOKS / TB), dim3(512), 0, stream,
                     x, wgt, bias, out);
}